// Round 15
// baseline (214.810 us; speedup 1.0000x reference)
//
#include <hip/hip_runtime.h>
#include <math.h>

// ---------------- problem constants ----------------
#define GAMMA_ 0.01f
#define WARP_  134.4f
#define INFV   100000.0f
#define BIGV   1000000000.0f

#define B_  4
#define H_  192
#define TP_ 350
#define TQ_ 400

// ---------------- workspace layout (float offsets) ----------------
#define ACC_OFF 0
#define DTW_OFF 16                          // 8 results: [which*4 + b]
#define SLP_OFF 32                          // sum_h logs_p  [B][350]
#define SLQ_OFF (SLP_OFF + B_*TP_)          // sum_h logs_q  [B][400]
#define KL1_OFF 3072
#define KL1_NCOL 401
#define KL1_PITCHT 352
#define KL2_OFF (KL1_OFF + B_*KL1_NCOL*KL1_PITCHT)
#define KL2_NCOL 351
#define KL2_PITCHT 408

// LDS ring: 67 column slots x 416 bf16 (832 B each); +2 pad slots for dead-lane
// b128 overrun. Live window (RB=8, skew-1, live lanes<=50): writes<=8p+15,
// live reads>=8p-50 -> span 65 < 67, no alias.  (r7-validated geometry)
#define RING_SLOTS 67
#define RING_PITCH 416

typedef float f4_t __attribute__((ext_vector_type(4)));

__device__ __forceinline__ unsigned pk2(float a, float b) {
    unsigned ua = __float_as_uint(a), ub = __float_as_uint(b);
    ua = (ua + 0x7FFFu + ((ua >> 16) & 1u)) >> 16;          // RTN bf16 (low half)
    ub = (ub + 0x7FFFu + ((ub >> 16) & 1u)) & 0xFFFF0000u;  // RTN bf16 (high half)
    return ua | ub;
}
__device__ __forceinline__ int modS(int x) { return x - (x / RING_SLOTS) * RING_SLOTS; }

// blocks 0..11: per-position sums over h of logs_p / logs_q (+ zero accumulators,
// skipping ws[5],ws[6]); block 12: mask sums -> ws[5], ws[6].
__global__ void sl_kernel(const float* __restrict__ logs_p,
                          const float* __restrict__ logs_q,
                          const float* __restrict__ pmask,
                          const float* __restrict__ zmask,
                          float* __restrict__ ws) {
    if (blockIdx.x == 12) {
        int tid = threadIdx.x;
        float a5 = 0.f, a6 = 0.f;
        for (int v = tid; v < B_ * TP_; v += 256) a5 += pmask[v];
        for (int v = tid; v < B_ * TQ_; v += 256) a6 += zmask[v];
        __shared__ float s5[4], s6[4];
        for (int off = 32; off > 0; off >>= 1) { a5 += __shfl_xor(a5, off); a6 += __shfl_xor(a6, off); }
        if ((tid & 63) == 0) { s5[tid >> 6] = a5; s6[tid >> 6] = a6; }
        __syncthreads();
        if (tid == 0) {
            ws[5] = s5[0] + s5[1] + s5[2] + s5[3];
            ws[6] = s6[0] + s6[1] + s6[2] + s6[3];
        }
        return;
    }
    int t = blockIdx.x * 256 + threadIdx.x;
    if (t < 32 && t != 5 && t != 6) ws[ACC_OFF + t] = 0.f;
    if (t < B_ * TP_) {
        int b = t / TP_, i = t % TP_;
        const float* p = logs_p + (size_t)b * H_ * TP_ + i;
        float s = 0.f;
        for (int h = 0; h < H_; ++h) s += p[(size_t)h * TP_];
        ws[SLP_OFF + t] = s;
    } else if (t < B_ * TP_ + B_ * TQ_) {
        int t2 = t - B_ * TP_;
        int b = t2 / TQ_, j = t2 % TQ_;
        const float* p = logs_q + (size_t)b * H_ * TQ_ + j;
        float s = 0.f;
        for (int h = 0; h < H_; ++h) s += p[(size_t)h * TQ_];
        ws[SLQ_OFF + t2] = s;
    }
}

// Writes the fully-masked D matrix (transposed, [J][I]) including pad row I=R and
// pad col J=C:  D = (pb&&qb) ? kl : (pb^qb ? INF : 0),  pb/qb false on pads.
__global__ void kl_kernel(const float* __restrict__ mp, const float* __restrict__ lsp,
                          const float* __restrict__ zp,
                          const float* __restrict__ mq, const float* __restrict__ lsq,
                          const float* __restrict__ zq,
                          const float* __restrict__ pmask, const float* __restrict__ zmask,
                          float* __restrict__ ws) {
    int which = blockIdx.z >> 2;
    int b     = blockIdx.z & 3;
    const float *mS, *lS, *zS, *SLrow, *SLcol, *rm, *cm; float* out; int R, C, pitchT;
    if (which == 0) { mS=mp; lS=lsp; zS=zp; SLrow=ws+SLP_OFF; SLcol=ws+SLQ_OFF;
                      rm=pmask + b*TP_; cm=zmask + b*TQ_;
                      out=ws+KL1_OFF + (size_t)b*KL1_NCOL*KL1_PITCHT;
                      R=TP_; C=TQ_; pitchT=KL1_PITCHT; }
    else            { mS=mq; lS=lsq; zS=zq; SLrow=ws+SLQ_OFF; SLcol=ws+SLP_OFF;
                      rm=zmask + b*TQ_; cm=pmask + b*TP_;
                      out=ws+KL2_OFF + (size_t)b*KL2_NCOL*KL2_PITCHT;
                      R=TQ_; C=TP_; pitchT=KL2_PITCHT; }
    int i0 = blockIdx.x * 32;
    int j0 = blockIdx.y * 32;
    if (i0 > R || j0 > C) return;
    __shared__ __align__(16) float wS [16][32];
    __shared__ __align__(16) float mSh[16][32];
    __shared__ __align__(16) float zSh[16][32];
    const float* mB = mS + (size_t)b * H_ * R;
    const float* lB = lS + (size_t)b * H_ * R;
    const float* zB = zS + (size_t)b * H_ * C;
    int tx = threadIdx.x, ty = threadIdx.y;
    int t  = ty * 16 + tx;
    float a00 = 0.f, a01 = 0.f, a10 = 0.f, a11 = 0.f;
    for (int h0 = 0; h0 < H_; h0 += 16) {
        for (int e = t; e < 512; e += 256) {
            int hh = e >> 5, cc = e & 31;
            int h = h0 + hh;
            int gi = i0 + cc, gj = j0 + cc;
            float wv = 0.f, mv = 0.f;
            if (gi < R) {
                wv = __expf(-2.f * lB[(size_t)h * R + gi]);
                mv = mB[(size_t)h * R + gi];
            }
            wS[hh][cc] = wv; mSh[hh][cc] = mv;
            zSh[hh][cc] = (gj < C) ? zB[(size_t)h * C + gj] : 0.f;
        }
        __syncthreads();
#pragma unroll
        for (int kk = 0; kk < 16; ++kk) {
            float2 wv = *(const float2*)&wS [kk][tx * 2];
            float2 mv = *(const float2*)&mSh[kk][tx * 2];
            float2 zv = *(const float2*)&zSh[kk][ty * 2];
            float d;
            d = zv.x - mv.x; a00 += wv.x * d * d;
            d = zv.x - mv.y; a01 += wv.y * d * d;
            d = zv.y - mv.x; a10 += wv.x * d * d;
            d = zv.y - mv.y; a11 += wv.y * d * d;
        }
        __syncthreads();
    }
    float accs[2][2] = {{a00, a01}, {a10, a11}};
    for (int jj = 0; jj < 2; ++jj)
        for (int ii = 0; ii < 2; ++ii) {
            int I = i0 + tx * 2 + ii, J = j0 + ty * 2 + jj;
            if (I <= R && J <= C) {
                bool pbI = (I < R) && (rm[I] != 0.f);
                bool qbJ = (J < C) && (cm[J] != 0.f);
                float v;
                if (pbI & qbJ)
                    v = SLrow[b * R + I] - SLcol[b * C + J] - 0.5f * H_ + 0.5f * accs[jj][ii];
                else
                    v = (pbI ^ qbJ) ? INFV : 0.f;
                out[(size_t)J * pitchT + I] = v;
            }
        }
}

// stager macros: per-chunk banked loads (bank = chunk & 3) and bf16 ring stores
// (r12-validated: plain HIP loads, compiler-managed waits)
#define SLD2(BK, q) { int col_; \
    col_ = ((q) << 3) + cA; \
    if (vA && col_ <= C_) rA##BK = *(const f4_t*)(klT + (size_t)col_ * pitchT + (iA << 2)); \
    col_ = ((q) << 3) + cB; \
    if (vB && col_ <= C_) rB##BK = *(const f4_t*)(klT + (size_t)col_ * pitchT + (iB << 2)); }
#define SST2(BK, q) { int col_; \
    col_ = ((q) << 3) + cA; \
    if (vA && col_ <= C_) { int s_ = modS(col_); \
        uint2 u_; u_.x = pk2(rA##BK.x, rA##BK.y); u_.y = pk2(rA##BK.z, rA##BK.w); \
        *(uint2*)&ring[s_][iA << 2] = u_; } \
    col_ = ((q) << 3) + cB; \
    if (vB && col_ <= C_) { int s_ = modS(col_); \
        uint2 u_; u_.x = pk2(rB##BK.x, rB##BK.y); u_.y = pk2(rB##BK.z, rB##BK.w); \
        *(uint2*)&ring[s_][iB << 2] = u_; } }

// stager barrier: ds_writes visible, but NO vmcnt drain -> batch loads fly across
#define STAGER_BAR() { asm volatile("s_waitcnt lgkmcnt(0)" ::: "memory"); \
                       __builtin_amdgcn_s_barrier(); }

// Standalone soft-DTW: 8 blocks (which = bid>>2, b = bid&3), r7-validated consumer,
// r12-validated batched stager (loads up to 4 phases ahead, drain-free barrier).
__global__ __launch_bounds__(512, 1) void dtw_kernel(float* ws) {
    __shared__ __align__(16) unsigned short ring[RING_SLOTS + 2][RING_PITCH];
    int bid = blockIdx.x, tid = threadIdx.x;
    int b = bid & 3, which = bid >> 2;
    int R_, C_, pitchT;
    const float* klT;
    if (which == 0) {
        R_ = TP_; C_ = TQ_; pitchT = KL1_PITCHT;
        klT = ws + KL1_OFF + (size_t)b * KL1_NCOL * KL1_PITCHT;
    } else {
        R_ = TQ_; C_ = TP_; pitchT = KL2_PITCHT;
        klT = ws + KL2_OFF + (size_t)b * KL2_NCOL * KL2_PITCHT;
    }
    int lres = R_ >> 3;                   // 43 (kl1) / 50 (kl2)
    int kres = R_ & 7;                    // 6 / 0
    int tmax = C_ + lres;
    int P = (tmax >> 3) + 1;              // 56 / 51 phases of 8 steps

    if (tid < 64) {
        // ---------------- consumer wave (RB=8, skew-1) ----------------
        int lane = tid; bool lane0 = (lane == 0);
        float p0=BIGV,p1=BIGV,p2=BIGV,p3=BIGV,p4=BIGV,p5=BIGV,p6=BIGV,p7=BIGV;
        float recv_cur = BIGV, recv_prev = BIGV;
        __syncthreads();                  // B0: chunk 0 staged
        for (int ph = 0; ph < P; ++ph) {
            int t0 = ph << 3;
            int c0 = t0 - lane;
            int cr = c0 < 0 ? 0 : (c0 > C_ ? C_ : c0);
            int s0 = modS(cr);
            int4 rd = *(const int4*)&ring[s0][lane << 3];
#pragma unroll
            for (int i = 0; i < 8; ++i) {
                int c = t0 + i - lane;
                int4 ru = rd;
                if (i < 7) {              // prefetch next column (within staged chunks)
                    int cn = c + 1; cn = cn < 0 ? 0 : (cn > C_ ? C_ : cn);
                    int sn = modS(cn);
                    rd = *(const int4*)&ring[sn][lane << 3];
                }
                float last_ = 0.f;
                if ((unsigned)c <= (unsigned)C_) {
                    float u_  = lane0 ? BIGV : recv_cur;
                    float dg  = (c == 0) ? (lane0 ? 0.f : BIGV) : (lane0 ? BIGV : recv_prev);
                    float d0 = __uint_as_float((unsigned)ru.x << 16);
                    float d1 = __uint_as_float((unsigned)ru.x & 0xFFFF0000u);
                    float d2 = __uint_as_float((unsigned)ru.y << 16);
                    float d3 = __uint_as_float((unsigned)ru.y & 0xFFFF0000u);
                    float d4 = __uint_as_float((unsigned)ru.z << 16);
                    float d5 = __uint_as_float((unsigned)ru.z & 0xFFFF0000u);
                    float d6 = __uint_as_float((unsigned)ru.w << 16);
                    float d7 = __uint_as_float((unsigned)ru.w & 0xFFFF0000u);
                    float B0 = WARP_ + d0, B1 = WARP_ + d1, B2 = WARP_ + d2, B3 = WARP_ + d3;
                    float B4 = WARP_ + d4, B5 = WARP_ + d5, B6 = WARP_ + d6, B7 = WARP_ + d7;
                    float P0 = fminf(dg + d0, p0 + B0);
                    float P1 = fminf(p0 + d1, p1 + B1);
                    float P2 = fminf(p1 + d2, p2 + B2);
                    float P3 = fminf(p2 + d3, p3 + B3);
                    float P4 = fminf(p3 + d4, p4 + B4);
                    float P5 = fminf(p4 + d5, p5 + B5);
                    float P6 = fminf(p5 + d6, p6 + B6);
                    float P7 = fminf(p6 + d7, p7 + B7);
                    u_ = fminf(P0, u_ + B0); p0 = u_;
                    u_ = fminf(P1, u_ + B1); p1 = u_;
                    u_ = fminf(P2, u_ + B2); p2 = u_;
                    u_ = fminf(P3, u_ + B3); p3 = u_;
                    u_ = fminf(P4, u_ + B4); p4 = u_;
                    u_ = fminf(P5, u_ + B5); p5 = u_;
                    u_ = fminf(P6, u_ + B6); p6 = u_;
                    u_ = fminf(P7, u_ + B7); p7 = u_;
                    last_ = u_;
                }
                recv_prev = recv_cur;
                recv_cur  = __shfl_up(last_, 1);
            }
            __syncthreads();              // chunk ph+1 writes complete
        }
        float q0 = __shfl(p0, lres), q1 = __shfl(p1, lres), q2 = __shfl(p2, lres),
              q3 = __shfl(p3, lres), q4 = __shfl(p4, lres), q5 = __shfl(p5, lres),
              q6 = __shfl(p6, lres), q7 = __shfl(p7, lres);
        if (lane0) {
            float res = (kres == 0) ? q0 : (kres == 1) ? q1 : (kres == 2) ? q2 :
                        (kres == 3) ? q3 : (kres == 4) ? q4 : (kres == 5) ? q5 :
                        (kres == 6) ? q6 : q7;
            ws[DTW_OFF + which * 4 + b] = res;
        }
    } else {
        // ------- stager waves (1..7): 4-phase batched loads, drain-free barrier -------
        int st  = tid - 64;               // 0..447
        int n4  = pitchT >> 2;            // 88 / 102 float4s per column
        int tot = n4 << 3;                // per-chunk elements (704 / 816)
        int cA = st / n4,  iA = st - cA * n4;
        int eB = st + 448; int cB = eB / n4, iB = eB - cB * n4;
        bool vA = st < tot, vB = eB < tot;
        f4_t rA0={0,0,0,0}, rA1={0,0,0,0}, rA2={0,0,0,0}, rA3={0,0,0,0};
        f4_t rB0={0,0,0,0}, rB1={0,0,0,0}, rB2={0,0,0,0}, rB3={0,0,0,0};
        SLD2(0, 0)                        // chunk 0 -> bank 0
        SST2(0, 0)
        SLD2(1, 1)                        // chunk 1 -> bank 1
        STAGER_BAR();                     // B0
        for (int p = 0; p < P; ++p) {
            switch ((p + 1) & 3) {        // store chunk p+1 from bank (p+1)&3
                case 0: SST2(0, p + 1) break;
                case 1: SST2(1, p + 1) break;
                case 2: SST2(2, p + 1) break;
                default: SST2(3, p + 1) break;
            }
            if ((p & 3) == 0) {           // batch: chunks p+2..p+5 -> banks 2,3,0,1
                SLD2(2, p + 2) SLD2(3, p + 3) SLD2(0, p + 4) SLD2(1, p + 5)
            }
            STAGER_BAR();
        }
    }
}

// Standalone streaming reductions: full occupancy, 2040 blocks, unroll x4,
// nontemporal loads (zero reuse; L3-resident replays proved tier-independence).
__global__ __launch_bounds__(512) void red_kernel(
    const float* __restrict__ mel, const float* __restrict__ melh,
    const float* __restrict__ sg,  const float* __restrict__ se,
    const float* __restrict__ fr,  const float* __restrict__ ff,
    const float* __restrict__ dur, float* ws) {
    __shared__ float sb[64];
    int tid = threadIdx.x;
    long T = (long)gridDim.x * 512;
    long gid = (long)blockIdx.x * 512 + tid;
    const f4_t* fr4   = (const f4_t*)fr;
    const f4_t* ff4   = (const f4_t*)ff;
    const float4* sg4   = (const float4*)sg;
    const float4* se4   = (const float4*)se;
    const float4* mel4  = (const float4*)mel;
    const float4* melh4 = (const float4*)melh;
    const float4* dur4  = (const float4*)dur;
    const long E0 = 12582912;             // feats float4s (97% of bytes)
    float a2 = 0.f;
    long v = gid;
    for (; v + 3 * T < E0; v += 4 * T) {  // 8 independent nt loads in flight
        f4_t x0 = __builtin_nontemporal_load(fr4 + v);
        f4_t y0 = __builtin_nontemporal_load(ff4 + v);
        f4_t x1 = __builtin_nontemporal_load(fr4 + v + T);
        f4_t y1 = __builtin_nontemporal_load(ff4 + v + T);
        f4_t x2 = __builtin_nontemporal_load(fr4 + v + 2 * T);
        f4_t y2 = __builtin_nontemporal_load(ff4 + v + 2 * T);
        f4_t x3 = __builtin_nontemporal_load(fr4 + v + 3 * T);
        f4_t y3 = __builtin_nontemporal_load(ff4 + v + 3 * T);
        a2 += fabsf(x0.x-y0.x)+fabsf(x0.y-y0.y)+fabsf(x0.z-y0.z)+fabsf(x0.w-y0.w);
        a2 += fabsf(x1.x-y1.x)+fabsf(x1.y-y1.y)+fabsf(x1.z-y1.z)+fabsf(x1.w-y1.w);
        a2 += fabsf(x2.x-y2.x)+fabsf(x2.y-y2.y)+fabsf(x2.z-y2.z)+fabsf(x2.w-y2.w);
        a2 += fabsf(x3.x-y3.x)+fabsf(x3.y-y3.y)+fabsf(x3.z-y3.z)+fabsf(x3.w-y3.w);
    }
    for (; v < E0; v += T) {
        f4_t x = __builtin_nontemporal_load(fr4 + v);
        f4_t y = __builtin_nontemporal_load(ff4 + v);
        a2 += fabsf(x.x-y.x)+fabsf(x.y-y.y)+fabsf(x.z-y.z)+fabsf(x.w-y.w);
    }
    float a0=0.f, a1=0.f, a3=0.f, a4=0.f;
    long w = gid;                         // tail: 108,894 float4s, <=1 per thread
    if (w < 108894) {
        if (w < 49152) {
            float4 s = sg4[w]; float e;
            e=1.f-s.x; a0+=e*e; e=1.f-s.y; a0+=e*e; e=1.f-s.z; a0+=e*e; e=1.f-s.w; a0+=e*e;
        } else if (w < 98304) {
            float4 s = se4[w - 49152]; float e;
            e=1.f-s.x; a1+=e*e; e=1.f-s.y; a1+=e*e; e=1.f-s.z; a1+=e*e; e=1.f-s.w; a1+=e*e;
        } else if (w < 108544) {
            float4 x = mel4[w - 98304], y = melh4[w - 98304];
            a3 += fabsf(x.x-y.x)+fabsf(x.y-y.y)+fabsf(x.z-y.z)+fabsf(x.w-y.w);
        } else {
            float4 x = dur4[w - 108544]; a4 += x.x + x.y + x.z + x.w;
        }
    }
    float vals[5] = {a0, a1, a2, a3, a4};
#pragma unroll
    for (int q = 0; q < 5; ++q) {
        float x = vals[q];
        for (int off = 32; off > 0; off >>= 1) x += __shfl_xor(x, off);
        if ((tid & 63) == 0) sb[(tid >> 6) * 8 + q] = x;
    }
    __syncthreads();
    if (tid < 5) {
        float s = 0.f;
        for (int w2 = 0; w2 < 8; ++w2) s += sb[w2 * 8 + tid];
        atomicAdd(&ws[ACC_OFF + tid], s);
    }
}

__global__ void final_kernel(const float* __restrict__ ws,
                             const float* __restrict__ ldl,
                             float* __restrict__ out) {
    if (threadIdx.x == 0 && blockIdx.x == 0) {
        float gen  = ws[0] * (1.f / 32768.f);
        float e2e  = ws[1] * (1.f / 32768.f);
        float fm   = ws[2] * (2.f / 2097152.f);
        float melv = ws[3] * (45.f / 40960.f);
        float durv = ws[4];
        float dlen = logf(ldl[0] + 1e-6f);
        float kl  = (ws[DTW_OFF + 0] + ws[DTW_OFF + 1] + ws[DTW_OFF + 2] + ws[DTW_OFF + 3]) / ws[5];
        float klf = (ws[DTW_OFF + 4] + ws[DTW_OFF + 5] + ws[DTW_OFF + 6] + ws[DTW_OFF + 7]) / ws[6];
        out[0] = gen + e2e + fm + melv + durv + dlen + kl + klf;
    }
}

extern "C" void kernel_launch(void* const* d_in, const int* in_sizes, int n_in,
                              void* d_out, int out_size, void* d_ws, size_t ws_size,
                              hipStream_t stream) {
    const float* mel    = (const float*)d_in[0];
    const float* melh   = (const float*)d_in[1];
    const float* sg     = (const float*)d_in[2];
    const float* se     = (const float*)d_in[3];
    const float* fr     = (const float*)d_in[4];
    const float* ff     = (const float*)d_in[5];
    const float* dur    = (const float*)d_in[6];
    const float* ldl    = (const float*)d_in[7];
    // d_in[8] = loss_pitch (unused by reference)
    const float* z_p    = (const float*)d_in[9];
    const float* m_p    = (const float*)d_in[10];
    const float* logs_p = (const float*)d_in[11];
    const float* z_q    = (const float*)d_in[12];
    const float* m_q    = (const float*)d_in[13];
    const float* logs_q = (const float*)d_in[14];
    const float* pmask  = (const float*)d_in[15];
    const float* zmask  = (const float*)d_in[16];  // (B,1,TQ) == flat (B,TQ)
    float* ws  = (float*)d_ws;
    float* out = (float*)d_out;

    sl_kernel<<<13, 256, 0, stream>>>(logs_p, logs_q, pmask, zmask, ws);
    kl_kernel<<<dim3(13, 13, 8), dim3(16, 16), 0, stream>>>(
        m_p, logs_p, z_p, m_q, logs_q, z_q, pmask, zmask, ws);
    dtw_kernel<<<8, 512, 0, stream>>>(ws);
    red_kernel<<<2040, 512, 0, stream>>>(mel, melh, sg, se, fr, ff, dur, ws);
    final_kernel<<<1, 64, 0, stream>>>(ws, ldl, out);
}

// Round 16
// 168.954 us; speedup vs baseline: 1.2714x; 1.2714x over previous
//
#include <hip/hip_runtime.h>
#include <math.h>

// ---------------- problem constants ----------------
#define GAMMA_ 0.01f
#define WARP_  134.4f
#define INFV   100000.0f
#define BIGV   1000000000.0f

#define B_  4
#define H_  192
#define TP_ 350
#define TQ_ 400

// ---------------- workspace layout (float offsets) ----------------
#define ACC_OFF 0
#define DTW_OFF 16                          // 8 results: [which*4 + b]
#define SLP_OFF 32                          // sum_h logs_p  [B][350]
#define SLQ_OFF (SLP_OFF + B_*TP_)          // sum_h logs_q  [B][400]
#define KL1_OFF 3072
#define KL1_NCOL 401
#define KL1_PITCHT 352
#define KL2_OFF (KL1_OFF + B_*KL1_NCOL*KL1_PITCHT)
#define KL2_NCOL 351
#define KL2_PITCHT 408

// LDS ring: 67 column slots x 416 bf16 (832 B each); +2 pad slots for dead-lane
// b128 overrun. Live window (RB=8, skew-1, live lanes<=50): writes<=8p+15,
// live reads>=8p-50 -> span 65 < 67, no alias.  (r7-validated geometry)
#define RING_SLOTS 67
#define RING_PITCH 416

typedef float f4_t __attribute__((ext_vector_type(4)));

__device__ __forceinline__ unsigned pk2(float a, float b) {
    unsigned ua = __float_as_uint(a), ub = __float_as_uint(b);
    ua = (ua + 0x7FFFu + ((ua >> 16) & 1u)) >> 16;          // RTN bf16 (low half)
    ub = (ub + 0x7FFFu + ((ub >> 16) & 1u)) & 0xFFFF0000u;  // RTN bf16 (high half)
    return ua | ub;
}
__device__ __forceinline__ int modS(int x) { return x - (x / RING_SLOTS) * RING_SLOTS; }

// blocks 0..11: per-position sums over h of logs_p / logs_q (+ zero accumulators,
// skipping ws[5],ws[6]); block 12: mask sums -> ws[5], ws[6].
__global__ void sl_kernel(const float* __restrict__ logs_p,
                          const float* __restrict__ logs_q,
                          const float* __restrict__ pmask,
                          const float* __restrict__ zmask,
                          float* __restrict__ ws) {
    if (blockIdx.x == 12) {
        int tid = threadIdx.x;
        float a5 = 0.f, a6 = 0.f;
        for (int v = tid; v < B_ * TP_; v += 256) a5 += pmask[v];
        for (int v = tid; v < B_ * TQ_; v += 256) a6 += zmask[v];
        __shared__ float s5[4], s6[4];
        for (int off = 32; off > 0; off >>= 1) { a5 += __shfl_xor(a5, off); a6 += __shfl_xor(a6, off); }
        if ((tid & 63) == 0) { s5[tid >> 6] = a5; s6[tid >> 6] = a6; }
        __syncthreads();
        if (tid == 0) {
            ws[5] = s5[0] + s5[1] + s5[2] + s5[3];
            ws[6] = s6[0] + s6[1] + s6[2] + s6[3];
        }
        return;
    }
    int t = blockIdx.x * 256 + threadIdx.x;
    if (t < 32 && t != 5 && t != 6) ws[ACC_OFF + t] = 0.f;
    if (t < B_ * TP_) {
        int b = t / TP_, i = t % TP_;
        const float* p = logs_p + (size_t)b * H_ * TP_ + i;
        float s = 0.f;
        for (int h = 0; h < H_; ++h) s += p[(size_t)h * TP_];
        ws[SLP_OFF + t] = s;
    } else if (t < B_ * TP_ + B_ * TQ_) {
        int t2 = t - B_ * TP_;
        int b = t2 / TQ_, j = t2 % TQ_;
        const float* p = logs_q + (size_t)b * H_ * TQ_ + j;
        float s = 0.f;
        for (int h = 0; h < H_; ++h) s += p[(size_t)h * TQ_];
        ws[SLQ_OFF + t2] = s;
    }
}

// Writes the fully-masked D matrix (transposed, [J][I]) including pad row I=R and
// pad col J=C:  D = (pb&&qb) ? kl : (pb^qb ? INF : 0),  pb/qb false on pads.
__global__ void kl_kernel(const float* __restrict__ mp, const float* __restrict__ lsp,
                          const float* __restrict__ zp,
                          const float* __restrict__ mq, const float* __restrict__ lsq,
                          const float* __restrict__ zq,
                          const float* __restrict__ pmask, const float* __restrict__ zmask,
                          float* __restrict__ ws) {
    int which = blockIdx.z >> 2;
    int b     = blockIdx.z & 3;
    const float *mS, *lS, *zS, *SLrow, *SLcol, *rm, *cm; float* out; int R, C, pitchT;
    if (which == 0) { mS=mp; lS=lsp; zS=zp; SLrow=ws+SLP_OFF; SLcol=ws+SLQ_OFF;
                      rm=pmask + b*TP_; cm=zmask + b*TQ_;
                      out=ws+KL1_OFF + (size_t)b*KL1_NCOL*KL1_PITCHT;
                      R=TP_; C=TQ_; pitchT=KL1_PITCHT; }
    else            { mS=mq; lS=lsq; zS=zq; SLrow=ws+SLQ_OFF; SLcol=ws+SLP_OFF;
                      rm=zmask + b*TQ_; cm=pmask + b*TP_;
                      out=ws+KL2_OFF + (size_t)b*KL2_NCOL*KL2_PITCHT;
                      R=TQ_; C=TP_; pitchT=KL2_PITCHT; }
    int i0 = blockIdx.x * 32;
    int j0 = blockIdx.y * 32;
    if (i0 > R || j0 > C) return;
    __shared__ __align__(16) float wS [16][32];
    __shared__ __align__(16) float mSh[16][32];
    __shared__ __align__(16) float zSh[16][32];
    const float* mB = mS + (size_t)b * H_ * R;
    const float* lB = lS + (size_t)b * H_ * R;
    const float* zB = zS + (size_t)b * H_ * C;
    int tx = threadIdx.x, ty = threadIdx.y;
    int t  = ty * 16 + tx;
    float a00 = 0.f, a01 = 0.f, a10 = 0.f, a11 = 0.f;
    for (int h0 = 0; h0 < H_; h0 += 16) {
        for (int e = t; e < 512; e += 256) {
            int hh = e >> 5, cc = e & 31;
            int h = h0 + hh;
            int gi = i0 + cc, gj = j0 + cc;
            float wv = 0.f, mv = 0.f;
            if (gi < R) {
                wv = __expf(-2.f * lB[(size_t)h * R + gi]);
                mv = mB[(size_t)h * R + gi];
            }
            wS[hh][cc] = wv; mSh[hh][cc] = mv;
            zSh[hh][cc] = (gj < C) ? zB[(size_t)h * C + gj] : 0.f;
        }
        __syncthreads();
#pragma unroll
        for (int kk = 0; kk < 16; ++kk) {
            float2 wv = *(const float2*)&wS [kk][tx * 2];
            float2 mv = *(const float2*)&mSh[kk][tx * 2];
            float2 zv = *(const float2*)&zSh[kk][ty * 2];
            float d;
            d = zv.x - mv.x; a00 += wv.x * d * d;
            d = zv.x - mv.y; a01 += wv.y * d * d;
            d = zv.y - mv.x; a10 += wv.x * d * d;
            d = zv.y - mv.y; a11 += wv.y * d * d;
        }
        __syncthreads();
    }
    float accs[2][2] = {{a00, a01}, {a10, a11}};
    for (int jj = 0; jj < 2; ++jj)
        for (int ii = 0; ii < 2; ++ii) {
            int I = i0 + tx * 2 + ii, J = j0 + ty * 2 + jj;
            if (I <= R && J <= C) {
                bool pbI = (I < R) && (rm[I] != 0.f);
                bool qbJ = (J < C) && (cm[J] != 0.f);
                float v;
                if (pbI & qbJ)
                    v = SLrow[b * R + I] - SLcol[b * C + J] - 0.5f * H_ + 0.5f * accs[jj][ii];
                else
                    v = (pbI ^ qbJ) ? INFV : 0.f;
                out[(size_t)J * pitchT + I] = v;
            }
        }
}

// stager macros: load chunk q (8 cols) element (cc,ii) from klT; store to ring (bf16)
#define SLD(q, r, cc, ii, vv) { int col_ = ((q) << 3) + (cc); \
    if ((vv) && col_ <= C_) r = *(const f4_t*)(klT + (size_t)col_ * pitchT + ((ii) << 2)); }
#define SST(q, r, cc, ii, vv) { int col_ = ((q) << 3) + (cc); \
    if ((vv) && col_ <= C_) { int s_ = modS(col_); \
        uint2 u_; u_.x = pk2(r.x, r.y); u_.y = pk2(r.z, r.w); \
        *(uint2*)&ring[s_][(ii) << 2] = u_; } }

// Fused: blocks 0..7 = soft-DTW producer/consumer LDS ring (r7-validated, RB=8,
//        simple 1-ahead stager); blocks 8.. = streaming reductions (nt, unroll x4).
__global__ __launch_bounds__(512, 1) void main_kernel(
    const float* __restrict__ mel, const float* __restrict__ melh,
    const float* __restrict__ sg,  const float* __restrict__ se,
    const float* __restrict__ fr,  const float* __restrict__ ff,
    const float* __restrict__ dur, float* ws) {
    __shared__ __align__(16) unsigned short ring[RING_SLOTS + 2][RING_PITCH];
    int bid = blockIdx.x, tid = threadIdx.x;
    if (bid < 8) {
        int b = bid & 3, which = bid >> 2;
        int R_, C_, pitchT;
        const float* klT;
        if (which == 0) {
            R_ = TP_; C_ = TQ_; pitchT = KL1_PITCHT;
            klT = ws + KL1_OFF + (size_t)b * KL1_NCOL * KL1_PITCHT;
        } else {
            R_ = TQ_; C_ = TP_; pitchT = KL2_PITCHT;
            klT = ws + KL2_OFF + (size_t)b * KL2_NCOL * KL2_PITCHT;
        }
        int lres = R_ >> 3;                   // 43 (kl1) / 50 (kl2)
        int kres = R_ & 7;                    // 6 / 0
        int tmax = C_ + lres;
        int P = (tmax >> 3) + 1;              // 56 / 51 phases of 8 steps

        if (tid < 64) {
            // ---------------- consumer wave (RB=8, skew-1) ----------------
            int lane = tid; bool lane0 = (lane == 0);
            float p0=BIGV,p1=BIGV,p2=BIGV,p3=BIGV,p4=BIGV,p5=BIGV,p6=BIGV,p7=BIGV;
            float recv_cur = BIGV, recv_prev = BIGV;
            __syncthreads();                  // B0: chunk 0 staged
            for (int ph = 0; ph < P; ++ph) {
                int t0 = ph << 3;
                int c0 = t0 - lane;
                int cr = c0 < 0 ? 0 : (c0 > C_ ? C_ : c0);
                int s0 = modS(cr);
                int4 rd = *(const int4*)&ring[s0][lane << 3];
#pragma unroll
                for (int i = 0; i < 8; ++i) {
                    int c = t0 + i - lane;
                    int4 ru = rd;
                    if (i < 7) {              // prefetch next column (within staged chunks)
                        int cn = c + 1; cn = cn < 0 ? 0 : (cn > C_ ? C_ : cn);
                        int sn = modS(cn);
                        rd = *(const int4*)&ring[sn][lane << 3];
                    }
                    float last_ = 0.f;
                    if ((unsigned)c <= (unsigned)C_) {
                        float u_  = lane0 ? BIGV : recv_cur;
                        float dg  = (c == 0) ? (lane0 ? 0.f : BIGV) : (lane0 ? BIGV : recv_prev);
                        float d0 = __uint_as_float((unsigned)ru.x << 16);
                        float d1 = __uint_as_float((unsigned)ru.x & 0xFFFF0000u);
                        float d2 = __uint_as_float((unsigned)ru.y << 16);
                        float d3 = __uint_as_float((unsigned)ru.y & 0xFFFF0000u);
                        float d4 = __uint_as_float((unsigned)ru.z << 16);
                        float d5 = __uint_as_float((unsigned)ru.z & 0xFFFF0000u);
                        float d6 = __uint_as_float((unsigned)ru.w << 16);
                        float d7 = __uint_as_float((unsigned)ru.w & 0xFFFF0000u);
                        float B0 = WARP_ + d0, B1 = WARP_ + d1, B2 = WARP_ + d2, B3 = WARP_ + d3;
                        float B4 = WARP_ + d4, B5 = WARP_ + d5, B6 = WARP_ + d6, B7 = WARP_ + d7;
                        float P0 = fminf(dg + d0, p0 + B0);
                        float P1 = fminf(p0 + d1, p1 + B1);
                        float P2 = fminf(p1 + d2, p2 + B2);
                        float P3 = fminf(p2 + d3, p3 + B3);
                        float P4 = fminf(p3 + d4, p4 + B4);
                        float P5 = fminf(p4 + d5, p5 + B5);
                        float P6 = fminf(p5 + d6, p6 + B6);
                        float P7 = fminf(p6 + d7, p7 + B7);
                        u_ = fminf(P0, u_ + B0); p0 = u_;
                        u_ = fminf(P1, u_ + B1); p1 = u_;
                        u_ = fminf(P2, u_ + B2); p2 = u_;
                        u_ = fminf(P3, u_ + B3); p3 = u_;
                        u_ = fminf(P4, u_ + B4); p4 = u_;
                        u_ = fminf(P5, u_ + B5); p5 = u_;
                        u_ = fminf(P6, u_ + B6); p6 = u_;
                        u_ = fminf(P7, u_ + B7); p7 = u_;
                        last_ = u_;
                    }
                    recv_prev = recv_cur;
                    recv_cur  = __shfl_up(last_, 1);
                }
                __syncthreads();              // chunk ph+1 writes complete
            }
            float q0 = __shfl(p0, lres), q1 = __shfl(p1, lres), q2 = __shfl(p2, lres),
                  q3 = __shfl(p3, lres), q4 = __shfl(p4, lres), q5 = __shfl(p5, lres),
                  q6 = __shfl(p6, lres), q7 = __shfl(p7, lres);
            if (lane0) {
                float res = (kres == 0) ? q0 : (kres == 1) ? q1 : (kres == 2) ? q2 :
                            (kres == 3) ? q3 : (kres == 4) ? q4 : (kres == 5) ? q5 :
                            (kres == 6) ? q6 : q7;
                ws[DTW_OFF + which * 4 + b] = res;
            }
        } else {
            // ---------------- stager waves (1..7), 1-phase load slack ----------------
            int st  = tid - 64;               // 0..447
            int n4  = pitchT >> 2;            // 88 / 102 float4s per column
            int tot = n4 << 3;                // per-chunk elements (704 / 816)
            int cA = st / n4,  iA = st - cA * n4;
            int eB = st + 448; int cB = eB / n4, iB = eB - cB * n4;
            bool vA = st < tot, vB = eB < tot;
            f4_t rA = {0.f,0.f,0.f,0.f}, rB = {0.f,0.f,0.f,0.f};
            SLD(0, rA, cA, iA, vA) SLD(0, rB, cB, iB, vB)
            SST(0, rA, cA, iA, vA) SST(0, rB, cB, iB, vB)
            SLD(1, rA, cA, iA, vA) SLD(1, rB, cB, iB, vB)
            __syncthreads();                  // B0
            for (int p = 0; p < P; ++p) {
                SST(p + 1, rA, cA, iA, vA) SST(p + 1, rB, cB, iB, vB)
                SLD(p + 2, rA, cA, iA, vA) SLD(p + 2, rB, cB, iB, vB)
                __syncthreads();
            }
        }
    } else {
        // -------- reductions: nontemporal loads, unroll x4 (8 loads in flight) --------
        int rid = bid - 8;
        long T = (long)(gridDim.x - 8) * 512;
        long gid = (long)rid * 512 + tid;
        const f4_t* fr4   = (const f4_t*)fr;
        const f4_t* ff4   = (const f4_t*)ff;
        const float4* sg4   = (const float4*)sg;
        const float4* se4   = (const float4*)se;
        const float4* mel4  = (const float4*)mel;
        const float4* melh4 = (const float4*)melh;
        const float4* dur4  = (const float4*)dur;
        const long E0 = 12582912;             // feats float4s (97% of bytes)
        float a2 = 0.f;
        long v = gid;
        for (; v + 3 * T < E0; v += 4 * T) {
            f4_t x0 = __builtin_nontemporal_load(fr4 + v);
            f4_t y0 = __builtin_nontemporal_load(ff4 + v);
            f4_t x1 = __builtin_nontemporal_load(fr4 + v + T);
            f4_t y1 = __builtin_nontemporal_load(ff4 + v + T);
            f4_t x2 = __builtin_nontemporal_load(fr4 + v + 2 * T);
            f4_t y2 = __builtin_nontemporal_load(ff4 + v + 2 * T);
            f4_t x3 = __builtin_nontemporal_load(fr4 + v + 3 * T);
            f4_t y3 = __builtin_nontemporal_load(ff4 + v + 3 * T);
            a2 += fabsf(x0.x-y0.x)+fabsf(x0.y-y0.y)+fabsf(x0.z-y0.z)+fabsf(x0.w-y0.w);
            a2 += fabsf(x1.x-y1.x)+fabsf(x1.y-y1.y)+fabsf(x1.z-y1.z)+fabsf(x1.w-y1.w);
            a2 += fabsf(x2.x-y2.x)+fabsf(x2.y-y2.y)+fabsf(x2.z-y2.z)+fabsf(x2.w-y2.w);
            a2 += fabsf(x3.x-y3.x)+fabsf(x3.y-y3.y)+fabsf(x3.z-y3.z)+fabsf(x3.w-y3.w);
        }
        for (; v < E0; v += T) {
            f4_t x = __builtin_nontemporal_load(fr4 + v);
            f4_t y = __builtin_nontemporal_load(ff4 + v);
            a2 += fabsf(x.x-y.x)+fabsf(x.y-y.y)+fabsf(x.z-y.z)+fabsf(x.w-y.w);
        }
        float a0=0.f, a1=0.f, a3=0.f, a4=0.f;
        long w = gid;                         // tail: 108,894 float4s, <=1 per thread
        if (w < 108894) {
            if (w < 49152) {
                float4 s = sg4[w]; float e;
                e=1.f-s.x; a0+=e*e; e=1.f-s.y; a0+=e*e; e=1.f-s.z; a0+=e*e; e=1.f-s.w; a0+=e*e;
            } else if (w < 98304) {
                float4 s = se4[w - 49152]; float e;
                e=1.f-s.x; a1+=e*e; e=1.f-s.y; a1+=e*e; e=1.f-s.z; a1+=e*e; e=1.f-s.w; a1+=e*e;
            } else if (w < 108544) {
                float4 x = mel4[w - 98304], y = melh4[w - 98304];
                a3 += fabsf(x.x-y.x)+fabsf(x.y-y.y)+fabsf(x.z-y.z)+fabsf(x.w-y.w);
            } else {
                float4 x = dur4[w - 108544]; a4 += x.x + x.y + x.z + x.w;
            }
        }
        float vals[5] = {a0, a1, a2, a3, a4};
        float* sb = (float*)ring;             // reduction blocks never touch the ring
#pragma unroll
        for (int q = 0; q < 5; ++q) {
            float x = vals[q];
            for (int off = 32; off > 0; off >>= 1) x += __shfl_xor(x, off);
            if ((tid & 63) == 0) sb[(tid >> 6) * 8 + q] = x;
        }
        __syncthreads();
        if (tid < 5) {
            float s = 0.f;
            for (int w2 = 0; w2 < 8; ++w2) s += sb[w2 * 8 + tid];
            atomicAdd(&ws[ACC_OFF + tid], s);
        }
    }
}

__global__ void final_kernel(const float* __restrict__ ws,
                             const float* __restrict__ ldl,
                             float* __restrict__ out) {
    if (threadIdx.x == 0 && blockIdx.x == 0) {
        float gen  = ws[0] * (1.f / 32768.f);
        float e2e  = ws[1] * (1.f / 32768.f);
        float fm   = ws[2] * (2.f / 2097152.f);
        float melv = ws[3] * (45.f / 40960.f);
        float durv = ws[4];
        float dlen = logf(ldl[0] + 1e-6f);
        float kl  = (ws[DTW_OFF + 0] + ws[DTW_OFF + 1] + ws[DTW_OFF + 2] + ws[DTW_OFF + 3]) / ws[5];
        float klf = (ws[DTW_OFF + 4] + ws[DTW_OFF + 5] + ws[DTW_OFF + 6] + ws[DTW_OFF + 7]) / ws[6];
        out[0] = gen + e2e + fm + melv + durv + dlen + kl + klf;
    }
}

extern "C" void kernel_launch(void* const* d_in, const int* in_sizes, int n_in,
                              void* d_out, int out_size, void* d_ws, size_t ws_size,
                              hipStream_t stream) {
    const float* mel    = (const float*)d_in[0];
    const float* melh   = (const float*)d_in[1];
    const float* sg     = (const float*)d_in[2];
    const float* se     = (const float*)d_in[3];
    const float* fr     = (const float*)d_in[4];
    const float* ff     = (const float*)d_in[5];
    const float* dur    = (const float*)d_in[6];
    const float* ldl    = (const float*)d_in[7];
    // d_in[8] = loss_pitch (unused by reference)
    const float* z_p    = (const float*)d_in[9];
    const float* m_p    = (const float*)d_in[10];
    const float* logs_p = (const float*)d_in[11];
    const float* z_q    = (const float*)d_in[12];
    const float* m_q    = (const float*)d_in[13];
    const float* logs_q = (const float*)d_in[14];
    const float* pmask  = (const float*)d_in[15];
    const float* zmask  = (const float*)d_in[16];  // (B,1,TQ) == flat (B,TQ)
    float* ws  = (float*)d_ws;
    float* out = (float*)d_out;

    sl_kernel<<<13, 256, 0, stream>>>(logs_p, logs_q, pmask, zmask, ws);
    kl_kernel<<<dim3(13, 13, 8), dim3(16, 16), 0, stream>>>(
        m_p, logs_p, z_p, m_q, logs_q, z_q, pmask, zmask, ws);
    main_kernel<<<8 + 1016, 512, 0, stream>>>(mel, melh, sg, se, fr, ff, dur, ws);
    final_kernel<<<1, 64, 0, stream>>>(ws, ldl, out);
}